// Round 9
// baseline (1388.788 us; speedup 1.0000x reference)
//
#include <hip/hip_runtime.h>
#include <math.h>

#define RCAP 32   // LDS-staged neighbor rows per user (32 rows * 256B = 8KB/wave)

// ---------------- wave helpers (wave = 64 on gfx950) ----------------
__device__ __forceinline__ int wsumi(int v) {
#pragma unroll
    for (int o = 32; o > 0; o >>= 1) v += __shfl_xor(v, o, 64);
    return v;
}
// sum over the 16 lanes of a lane-group (lane bits 0..3)
__device__ __forceinline__ float grp16_sum(float v) {
    v += __shfl_xor(v, 1, 64);
    v += __shfl_xor(v, 2, 64);
    v += __shfl_xor(v, 4, 64);
    v += __shfl_xor(v, 8, 64);
    return v;
}
// sum across the 4 groups (lane bits 4..5)
__device__ __forceinline__ float xgrp_sum(float v) {
    v += __shfl_xor(v, 16, 64);
    v += __shfl_xor(v, 32, 64);
    return v;
}
__device__ __forceinline__ float4 xgrp_sum4(float4 a) {
    a.x = xgrp_sum(a.x); a.y = xgrp_sum(a.y);
    a.z = xgrp_sum(a.z); a.w = xgrp_sum(a.w);
    return a;
}

// ---------------- gim = l2norm(leaky(l2norm(feat) @ W + b)) ----------------
__global__ void k_gim(const float* __restrict__ feat, const float* __restrict__ W,
                      const float* __restrict__ bias, float* __restrict__ gim,
                      int NI, int F) {
    __shared__ float As[64][17];   // +1 pad
    __shared__ float Bs[16][64];
    __shared__ float rn[64];
    const int tid = threadIdx.x;
    const int r0 = blockIdx.x * 64;
    const int tr = tid >> 4, tc = tid & 15;     // compute mapping: 4x4 microtile
    const int lrow = tid >> 2, lk = (tid & 3) * 4;  // feat load mapping
    float acc[4][4];
#pragma unroll
    for (int i = 0; i < 4; ++i)
#pragma unroll
        for (int j = 0; j < 4; ++j) acc[i][j] = 0.f;
    float ssq = 0.f;
    const bool rowok = (r0 + lrow) < NI;

    for (int kb = 0; kb < F; kb += 16) {
        float4 av = make_float4(0.f, 0.f, 0.f, 0.f);
        if (rowok) av = *(const float4*)(feat + (size_t)(r0 + lrow) * F + kb + lk);
        As[lrow][lk + 0] = av.x; As[lrow][lk + 1] = av.y;
        As[lrow][lk + 2] = av.z; As[lrow][lk + 3] = av.w;
        ssq += av.x * av.x + av.y * av.y + av.z * av.z + av.w * av.w;
        float4 bv = *(const float4*)(W + (size_t)(kb + (tid >> 4)) * 64 + (tid & 15) * 4);
        *(float4*)&Bs[tid >> 4][(tid & 15) * 4] = bv;
        __syncthreads();
#pragma unroll
        for (int kk = 0; kk < 16; ++kk) {
            float a[4], b[4];
#pragma unroll
            for (int i = 0; i < 4; ++i) a[i] = As[tr * 4 + i][kk];
#pragma unroll
            for (int j = 0; j < 4; ++j) b[j] = Bs[kk][tc * 4 + j];
#pragma unroll
            for (int i = 0; i < 4; ++i)
#pragma unroll
                for (int j = 0; j < 4; ++j) acc[i][j] += a[i] * b[j];
        }
        __syncthreads();
    }
    ssq += __shfl_xor(ssq, 1, 64);
    ssq += __shfl_xor(ssq, 2, 64);
    if ((tid & 3) == 0) rn[lrow] = ssq;
    __syncthreads();

    float bc[4];
#pragma unroll
    for (int j = 0; j < 4; ++j) bc[j] = bias[tc * 4 + j];
#pragma unroll
    for (int i = 0; i < 4; ++i) {
        int r = tr * 4 + i;
        float inv = 1.0f / fmaxf(sqrtf(rn[r]), 1e-12f);
        float v[4], rs = 0.f;
#pragma unroll
        for (int j = 0; j < 4; ++j) {
            float x = acc[i][j] * inv + bc[j];
            x = x > 0.f ? x : 0.01f * x;   // leaky_relu
            v[j] = x; rs += x * x;
        }
        rs += __shfl_xor(rs, 1, 64); rs += __shfl_xor(rs, 2, 64);
        rs += __shfl_xor(rs, 4, 64); rs += __shfl_xor(rs, 8, 64);
        float sc = 1.0f / fmaxf(sqrtf(rs), 1e-12f);
        int gr = r0 + r;
        if (gr < NI) {
            float4 o = make_float4(v[0] * sc, v[1] * sc, v[2] * sc, v[3] * sc);
            *(float4*)(gim + (size_t)gr * 64 + tc * 4) = o;
        }
    }
}

// ---------------- CSR/CSC build ----------------
__global__ void k_hist(const int* __restrict__ rows, const int* __restrict__ cols, int E,
                       int* __restrict__ cu, int* __restrict__ ci,
                       int* __restrict__ ranku, int* __restrict__ ranki) {
    for (int e = blockIdx.x * blockDim.x + threadIdx.x; e < E; e += gridDim.x * blockDim.x) {
        ranku[e] = atomicAdd(&cu[rows[e]], 1);
        ranki[e] = atomicAdd(&ci[cols[e]], 1);
    }
}

__global__ void k_bsum(const int* __restrict__ cnt, int n, int* __restrict__ bsum) {
    int i = blockIdx.x * 256 + threadIdx.x;
    int v = (i < n) ? cnt[i] : 0;
    v = wsumi(v);
    __shared__ int sm[4];
    if ((threadIdx.x & 63) == 0) sm[threadIdx.x >> 6] = v;
    __syncthreads();
    if (threadIdx.x == 0) bsum[blockIdx.x] = sm[0] + sm[1] + sm[2] + sm[3];
}

// single block, nb <= 512
__global__ void k_bscan(const int* __restrict__ bsum, int nb, int* __restrict__ bscan) {
    __shared__ int sd[512];
    int tid = threadIdx.x;
    int v = (tid < nb) ? bsum[tid] : 0;
    sd[tid] = v;
    __syncthreads();
    for (int off = 1; off < 512; off <<= 1) {
        int t = (tid >= off) ? sd[tid - off] : 0;
        __syncthreads();
        sd[tid] += t;
        __syncthreads();
    }
    if (tid < nb) bscan[tid] = sd[tid] - v;   // exclusive
}

__global__ void k_scan2(const int* __restrict__ cnt, int n, const int* __restrict__ bscan,
                        int* __restrict__ ptr) {
    __shared__ int sd[256];
    int tid = threadIdx.x;
    int i = blockIdx.x * 256 + tid;
    int v = (i < n) ? cnt[i] : 0;
    sd[tid] = v;
    __syncthreads();
    for (int off = 1; off < 256; off <<= 1) {
        int t = (tid >= off) ? sd[tid - off] : 0;
        __syncthreads();
        sd[tid] += t;
        __syncthreads();
    }
    if (i < n) ptr[i + 1] = sd[tid] + bscan[blockIdx.x];
    if (blockIdx.x == 0 && tid == 0) ptr[0] = 0;
}

// atomic-free scatter: csr[pu] = {col, csc_pos}; csc_r[pi] = row.
__global__ void k_scatter(const int* __restrict__ rows, const int* __restrict__ cols, int E,
                          const int* __restrict__ ranku, const int* __restrict__ ranki,
                          const int* __restrict__ rptr, const int* __restrict__ cptr,
                          int2* __restrict__ csr, int* __restrict__ csc_r) {
    for (int e = blockIdx.x * blockDim.x + threadIdx.x; e < E; e += gridDim.x * blockDim.x) {
        int r = rows[e], c = cols[e];
        int pu = rptr[r] + ranku[e];
        int pi = cptr[c] + ranki[e];
        csr[pu] = make_int2(c, pi);
        csc_r[pi] = r;
    }
}

// ---------------- routing: one wave per user; 16 lanes x 4 edges per iter ----------
// lane = 16*q + r: group q handles edge j0+q, lane holds dims [4r,4r+4).
// Iteration 0 is FUSED with LDS staging: gim rows are gathered once, written to
// this wave's private LDS slice, and reused by iterations 1,2 and the final pass.
// Rows beyond RCAP (deg>32, rare) fall back to the direct gather path.
__global__ void __launch_bounds__(256) k_route(
        const float* __restrict__ Gum, const float* __restrict__ gim,
        const int* __restrict__ rptr, const int2* __restrict__ csr,
        float* __restrict__ gum_out, float* __restrict__ gu,
        float* __restrict__ expw_csc, int NU) {
    __shared__ float tile[4 * RCAP * 64];    // 32 KB: 4 waves x 32 rows x 64 f32
    int wid = (blockIdx.x * blockDim.x + threadIdx.x) >> 6;
    int lane = threadIdx.x & 63;
    if (wid >= NU) return;
    const int q = lane >> 4, r = lane & 15;
    float* my = tile + (threadIdx.x >> 6) * (RCAP * 64);
    const size_t ubase = (size_t)wid * 64 + 4 * r;

    float4 gl = *(const float4*)(Gum + ubase);
    float s2 = grp16_sum(gl.x * gl.x + gl.y * gl.y + gl.z * gl.z + gl.w * gl.w);
    float inv = 1.0f / fmaxf(sqrtf(s2), 1e-12f);
    gl.x *= inv; gl.y *= inv; gl.z *= inv; gl.w *= inv;

    const int st = rptr[wid], en = rptr[wid + 1];
    const int enc = min(en, st + RCAP);      // staged prefix

    // ---- pass 0 (fused with staging): gather gim rows, stash in LDS ----
    {
        float s = 0.f;
        float4 acc = make_float4(0.f, 0.f, 0.f, 0.f);
        for (int j0 = st; j0 < en; j0 += 4) {
            int j = j0 + q;
            bool valid = j < en;
            int c = valid ? csr[j].x : 0;
            float4 gv = *(const float4*)(gim + (size_t)c * 64 + 4 * r);
            if (j < enc) *(float4*)(my + (j - st) * 64 + 4 * r) = gv;
            float d = grp16_sum(gl.x * gv.x + gl.y * gv.y + gl.z * gv.z + gl.w * gv.w);
            float w = d > 0.f ? d : 0.01f * d;
            float ew = valid ? __expf(w) : 0.f;
            s += ew;
            acc.x += ew * gv.x; acc.y += ew * gv.y;
            acc.z += ew * gv.z; acc.w += ew * gv.w;
        }
        s = xgrp_sum(s);
        acc = xgrp_sum4(acc);
        float invs = 1.0f / (s + 1e-16f);
        gl.x += acc.x * invs; gl.y += acc.y * invs;
        gl.z += acc.z * invs; gl.w += acc.w * invs;
        s2 = grp16_sum(gl.x * gl.x + gl.y * gl.y + gl.z * gl.z + gl.w * gl.w);
        inv = 1.0f / fmaxf(sqrtf(s2), 1e-12f);
        gl.x *= inv; gl.y *= inv; gl.z *= inv; gl.w *= inv;
    }

    // ---- passes 1,2: neighbor rows from LDS (fallback gather past RCAP) ----
    for (int it = 0; it < 2; ++it) {
        float s = 0.f;
        float4 acc = make_float4(0.f, 0.f, 0.f, 0.f);
        for (int j0 = st; j0 < en; j0 += 4) {
            int j = j0 + q;
            bool valid = j < en;
            float4 gv;
            if (j < enc) {
                gv = *(const float4*)(my + (j - st) * 64 + 4 * r);
            } else {
                int c = valid ? csr[j].x : 0;
                gv = *(const float4*)(gim + (size_t)c * 64 + 4 * r);
            }
            float d = grp16_sum(gl.x * gv.x + gl.y * gv.y + gl.z * gv.z + gl.w * gv.w);
            float w = d > 0.f ? d : 0.01f * d;
            float ew = valid ? __expf(w) : 0.f;
            s += ew;
            acc.x += ew * gv.x; acc.y += ew * gv.y;
            acc.z += ew * gv.z; acc.w += ew * gv.w;
        }
        s = xgrp_sum(s);
        acc = xgrp_sum4(acc);
        float invs = 1.0f / (s + 1e-16f);
        gl.x += acc.x * invs; gl.y += acc.y * invs;
        gl.z += acc.z * invs; gl.w += acc.w * invs;
        s2 = grp16_sum(gl.x * gl.x + gl.y * gl.y + gl.z * gl.z + gl.w * gl.w);
        inv = 1.0f / fmaxf(sqrtf(s2), 1e-12f);
        gl.x *= inv; gl.y *= inv; gl.z *= inv; gl.w *= inv;
    }
    if (q == 0) *(float4*)(gum_out + ubase) = gl;

    // ---- final layer, user side: exp(w) -> CSC slot, emit gu ----
    float s = 0.f;
    float4 acc = make_float4(0.f, 0.f, 0.f, 0.f);
    for (int j0 = st; j0 < en; j0 += 4) {
        int j = j0 + q;
        bool valid = j < en;
        float4 gv;
        if (j < enc) {
            gv = *(const float4*)(my + (j - st) * 64 + 4 * r);
        } else {
            int c = valid ? csr[j].x : 0;
            gv = *(const float4*)(gim + (size_t)c * 64 + 4 * r);
        }
        float d = grp16_sum(gl.x * gv.x + gl.y * gv.y + gl.z * gv.z + gl.w * gv.w);
        float w = d > 0.f ? d : 0.01f * d;
        float ew = valid ? __expf(w) : 0.f;
        if (valid && r == 0) expw_csc[csr[j].y] = ew;
        s += ew;
        acc.x += ew * gv.x; acc.y += ew * gv.y;
        acc.z += ew * gv.z; acc.w += ew * gv.w;
    }
    s = xgrp_sum(s);
    acc = xgrp_sum4(acc);
    float invs = 1.0f / (s + 1e-16f);
    if (q == 0) {
        float4 o = make_float4(gl.x + acc.x * invs, gl.y + acc.y * invs,
                               gl.z + acc.z * invs, gl.w + acc.w * invs);
        *(float4*)(gu + ubase) = o;
    }
}

// ---------------- final layer, item side: one wave per item; 4 edges/iter ---------
__global__ void k_item(const float* __restrict__ gum, const float* __restrict__ gim,
                       const int* __restrict__ cptr, const int* __restrict__ csc_r,
                       const float* __restrict__ expw_csc,
                       float* __restrict__ gi, int NI) {
    int wid = (blockIdx.x * blockDim.x + threadIdx.x) >> 6;
    int lane = threadIdx.x & 63;
    if (wid >= NI) return;
    const int q = lane >> 4, r = lane & 15;
    const int st = cptr[wid], en = cptr[wid + 1];
    float s = 0.f;
    float4 acc = make_float4(0.f, 0.f, 0.f, 0.f);
    for (int j0 = st; j0 < en; j0 += 4) {
        int j = j0 + q;
        bool valid = j < en;
        int rr = valid ? csc_r[j] : 0;
        float ew = valid ? expw_csc[j] : 0.f;
        float4 gv = *(const float4*)(gum + (size_t)rr * 64 + 4 * r);
        s += ew;
        acc.x += ew * gv.x; acc.y += ew * gv.y;
        acc.z += ew * gv.z; acc.w += ew * gv.w;
    }
    s = xgrp_sum(s);
    acc = xgrp_sum4(acc);
    float invs = 1.0f / (s + 1e-16f);
    if (q == 0) {
        const size_t ib = (size_t)wid * 64 + 4 * r;
        float4 gm = *(const float4*)(gim + ib);
        float4 o = make_float4(gm.x + acc.x * invs, gm.y + acc.y * invs,
                               gm.z + acc.z * invs, gm.w + acc.w * invs);
        *(float4*)(gi + ib) = o;
    }
}

// ---------------- output: xui[b] = dot(gu[user[b]], gi[pos[b]]) ----------------
__global__ void k_out(const float* __restrict__ gu, const float* __restrict__ gi,
                      const int* __restrict__ user, const int* __restrict__ pos,
                      float* __restrict__ out, int B) {
    int wid = (blockIdx.x * blockDim.x + threadIdx.x) >> 6;
    int lane = threadIdx.x & 63;
    if (wid >= B) return;
    float v = gu[(size_t)user[wid] * 64 + lane] * gi[(size_t)pos[wid] * 64 + lane];
#pragma unroll
    for (int o = 32; o > 0; o >>= 1) v += __shfl_xor(v, o, 64);
    if (lane == 0) out[wid] = v;
}

extern "C" void kernel_launch(void* const* d_in, const int* in_sizes, int n_in,
                              void* d_out, int out_size, void* d_ws, size_t ws_size,
                              hipStream_t stream) {
    const float* Gum  = (const float*)d_in[0];
    const float* feat = (const float*)d_in[1];
    const float* W    = (const float*)d_in[2];
    const float* bias = (const float*)d_in[3];
    const int* rows   = (const int*)d_in[4];
    const int* cols   = (const int*)d_in[5];
    const int* user   = (const int*)d_in[6];
    const int* pos    = (const int*)d_in[7];
    float* out = (float*)d_out;

    const int D  = in_sizes[3];          // 64
    const int NU = in_sizes[0] / D;      // 100000
    const int F  = in_sizes[2] / D;      // 2048
    const int NI = in_sizes[1] / F;      // 50000
    const int E  = in_sizes[4];          // 2000000
    const int B  = in_sizes[6];          // 4096

    char* p = (char*)d_ws;
    auto alloc = [&](size_t bytes) -> void* {
        void* r = (void*)p;
        p += (bytes + 255) / 256 * 256;
        return r;
    };
    float* gum     = (float*)alloc((size_t)NU * 64 * 4);
    float* gim     = (float*)alloc((size_t)NI * 64 * 4);
    float* gu      = (float*)alloc((size_t)NU * 64 * 4);
    float* gi      = (float*)alloc((size_t)NI * 64 * 4);
    float* expw    = (float*)alloc((size_t)E * 4);        // CSC-ordered
    int* rptr      = (int*)alloc((size_t)(NU + 1) * 4);
    int* cptr      = (int*)alloc((size_t)(NI + 1) * 4);
    int* cu        = (int*)alloc((size_t)NU * 4);
    int* ci        = (int*)alloc((size_t)NI * 4);
    int* ranku     = (int*)alloc((size_t)E * 4);
    int* ranki     = (int*)alloc((size_t)E * 4);
    int2* csr      = (int2*)alloc((size_t)E * 8);         // {col, csc_pos}
    int* csc_r     = (int*)alloc((size_t)E * 4);
    int* bsumU     = (int*)alloc(1024 * 4);
    int* bscanU    = (int*)alloc(1024 * 4);
    int* bsumI     = (int*)alloc(1024 * 4);
    int* bscanI    = (int*)alloc(1024 * 4);

    const int gU = (NU + 255) / 256;   // 391 (<=512 for k_bscan)
    const int gI = (NI + 255) / 256;   // 196

    hipMemsetAsync(cu, 0, (size_t)NU * 4, stream);
    hipMemsetAsync(ci, 0, (size_t)NI * 4, stream);
    k_hist<<<2048, 256, 0, stream>>>(rows, cols, E, cu, ci, ranku, ranki);

    k_bsum<<<gU, 256, 0, stream>>>(cu, NU, bsumU);
    k_bscan<<<1, 512, 0, stream>>>(bsumU, gU, bscanU);
    k_scan2<<<gU, 256, 0, stream>>>(cu, NU, bscanU, rptr);

    k_bsum<<<gI, 256, 0, stream>>>(ci, NI, bsumI);
    k_bscan<<<1, 512, 0, stream>>>(bsumI, gI, bscanI);
    k_scan2<<<gI, 256, 0, stream>>>(ci, NI, bscanI, cptr);

    k_scatter<<<2048, 256, 0, stream>>>(rows, cols, E, ranku, ranki, rptr, cptr, csr, csc_r);

    k_gim<<<(NI + 63) / 64, 256, 0, stream>>>(feat, W, bias, gim, NI, F);
    k_route<<<(NU + 3) / 4, 256, 0, stream>>>(Gum, gim, rptr, csr, gum, gu, expw, NU);
    k_item<<<(NI + 3) / 4, 256, 0, stream>>>(gum, gim, cptr, csc_r, expw, gi, NI);
    k_out<<<(B + 3) / 4, 256, 0, stream>>>(gu, gi, user, pos, out, B);
}

// Round 10
// 1285.015 us; speedup vs baseline: 1.0808x; 1.0808x over previous
//
#include <hip/hip_runtime.h>
#include <math.h>

#define RCAP 16   // LDS-staged rows/wave: 4 waves * 16 rows * 256B = 16KB/block
                  // -> 8 blocks/CU (occupancy-neutral, unlike RCAP=32's 3/CU)

// ---------------- wave helpers (wave = 64 on gfx950) ----------------
__device__ __forceinline__ int wsumi(int v) {
#pragma unroll
    for (int o = 32; o > 0; o >>= 1) v += __shfl_xor(v, o, 64);
    return v;
}
// sum over the 16 lanes of a lane-group (lane bits 0..3)
__device__ __forceinline__ float grp16_sum(float v) {
    v += __shfl_xor(v, 1, 64);
    v += __shfl_xor(v, 2, 64);
    v += __shfl_xor(v, 4, 64);
    v += __shfl_xor(v, 8, 64);
    return v;
}
// sum across the 4 groups (lane bits 4..5)
__device__ __forceinline__ float xgrp_sum(float v) {
    v += __shfl_xor(v, 16, 64);
    v += __shfl_xor(v, 32, 64);
    return v;
}
__device__ __forceinline__ float4 xgrp_sum4(float4 a) {
    a.x = xgrp_sum(a.x); a.y = xgrp_sum(a.y);
    a.z = xgrp_sum(a.z); a.w = xgrp_sum(a.w);
    return a;
}

// ---------------- gim = l2norm(leaky(l2norm(feat) @ W + b)) ----------------
__global__ void k_gim(const float* __restrict__ feat, const float* __restrict__ W,
                      const float* __restrict__ bias, float* __restrict__ gim,
                      int NI, int F) {
    __shared__ float As[64][17];   // +1 pad
    __shared__ float Bs[16][64];
    __shared__ float rn[64];
    const int tid = threadIdx.x;
    const int r0 = blockIdx.x * 64;
    const int tr = tid >> 4, tc = tid & 15;     // compute mapping: 4x4 microtile
    const int lrow = tid >> 2, lk = (tid & 3) * 4;  // feat load mapping
    float acc[4][4];
#pragma unroll
    for (int i = 0; i < 4; ++i)
#pragma unroll
        for (int j = 0; j < 4; ++j) acc[i][j] = 0.f;
    float ssq = 0.f;
    const bool rowok = (r0 + lrow) < NI;

    for (int kb = 0; kb < F; kb += 16) {
        float4 av = make_float4(0.f, 0.f, 0.f, 0.f);
        if (rowok) av = *(const float4*)(feat + (size_t)(r0 + lrow) * F + kb + lk);
        As[lrow][lk + 0] = av.x; As[lrow][lk + 1] = av.y;
        As[lrow][lk + 2] = av.z; As[lrow][lk + 3] = av.w;
        ssq += av.x * av.x + av.y * av.y + av.z * av.z + av.w * av.w;
        float4 bv = *(const float4*)(W + (size_t)(kb + (tid >> 4)) * 64 + (tid & 15) * 4);
        *(float4*)&Bs[tid >> 4][(tid & 15) * 4] = bv;
        __syncthreads();
#pragma unroll
        for (int kk = 0; kk < 16; ++kk) {
            float a[4], b[4];
#pragma unroll
            for (int i = 0; i < 4; ++i) a[i] = As[tr * 4 + i][kk];
#pragma unroll
            for (int j = 0; j < 4; ++j) b[j] = Bs[kk][tc * 4 + j];
#pragma unroll
            for (int i = 0; i < 4; ++i)
#pragma unroll
                for (int j = 0; j < 4; ++j) acc[i][j] += a[i] * b[j];
        }
        __syncthreads();
    }
    ssq += __shfl_xor(ssq, 1, 64);
    ssq += __shfl_xor(ssq, 2, 64);
    if ((tid & 3) == 0) rn[lrow] = ssq;
    __syncthreads();

    float bc[4];
#pragma unroll
    for (int j = 0; j < 4; ++j) bc[j] = bias[tc * 4 + j];
#pragma unroll
    for (int i = 0; i < 4; ++i) {
        int r = tr * 4 + i;
        float inv = 1.0f / fmaxf(sqrtf(rn[r]), 1e-12f);
        float v[4], rs = 0.f;
#pragma unroll
        for (int j = 0; j < 4; ++j) {
            float x = acc[i][j] * inv + bc[j];
            x = x > 0.f ? x : 0.01f * x;   // leaky_relu
            v[j] = x; rs += x * x;
        }
        rs += __shfl_xor(rs, 1, 64); rs += __shfl_xor(rs, 2, 64);
        rs += __shfl_xor(rs, 4, 64); rs += __shfl_xor(rs, 8, 64);
        float sc = 1.0f / fmaxf(sqrtf(rs), 1e-12f);
        int gr = r0 + r;
        if (gr < NI) {
            float4 o = make_float4(v[0] * sc, v[1] * sc, v[2] * sc, v[3] * sc);
            *(float4*)(gim + (size_t)gr * 64 + tc * 4) = o;
        }
    }
}

// ---------------- CSR/CSC build ----------------
__global__ void k_hist(const int* __restrict__ rows, const int* __restrict__ cols, int E,
                       int* __restrict__ cu, int* __restrict__ ci,
                       int* __restrict__ ranku, int* __restrict__ ranki) {
    for (int e = blockIdx.x * blockDim.x + threadIdx.x; e < E; e += gridDim.x * blockDim.x) {
        ranku[e] = atomicAdd(&cu[rows[e]], 1);
        ranki[e] = atomicAdd(&ci[cols[e]], 1);
    }
}

__global__ void k_bsum(const int* __restrict__ cnt, int n, int* __restrict__ bsum) {
    int i = blockIdx.x * 256 + threadIdx.x;
    int v = (i < n) ? cnt[i] : 0;
    v = wsumi(v);
    __shared__ int sm[4];
    if ((threadIdx.x & 63) == 0) sm[threadIdx.x >> 6] = v;
    __syncthreads();
    if (threadIdx.x == 0) bsum[blockIdx.x] = sm[0] + sm[1] + sm[2] + sm[3];
}

// single block, nb <= 512
__global__ void k_bscan(const int* __restrict__ bsum, int nb, int* __restrict__ bscan) {
    __shared__ int sd[512];
    int tid = threadIdx.x;
    int v = (tid < nb) ? bsum[tid] : 0;
    sd[tid] = v;
    __syncthreads();
    for (int off = 1; off < 512; off <<= 1) {
        int t = (tid >= off) ? sd[tid - off] : 0;
        __syncthreads();
        sd[tid] += t;
        __syncthreads();
    }
    if (tid < nb) bscan[tid] = sd[tid] - v;   // exclusive
}

__global__ void k_scan2(const int* __restrict__ cnt, int n, const int* __restrict__ bscan,
                        int* __restrict__ ptr) {
    __shared__ int sd[256];
    int tid = threadIdx.x;
    int i = blockIdx.x * 256 + tid;
    int v = (i < n) ? cnt[i] : 0;
    sd[tid] = v;
    __syncthreads();
    for (int off = 1; off < 256; off <<= 1) {
        int t = (tid >= off) ? sd[tid - off] : 0;
        __syncthreads();
        sd[tid] += t;
        __syncthreads();
    }
    if (i < n) ptr[i + 1] = sd[tid] + bscan[blockIdx.x];
    if (blockIdx.x == 0 && tid == 0) ptr[0] = 0;
}

// atomic-free scatter: csr[pu] = {col, csc_pos}; csc_r[pi] = row.
__global__ void k_scatter(const int* __restrict__ rows, const int* __restrict__ cols, int E,
                          const int* __restrict__ ranku, const int* __restrict__ ranki,
                          const int* __restrict__ rptr, const int* __restrict__ cptr,
                          int2* __restrict__ csr, int* __restrict__ csc_r) {
    for (int e = blockIdx.x * blockDim.x + threadIdx.x; e < E; e += gridDim.x * blockDim.x) {
        int r = rows[e], c = cols[e];
        int pu = rptr[r] + ranku[e];
        int pi = cptr[c] + ranki[e];
        csr[pu] = make_int2(c, pi);
        csc_r[pi] = r;
    }
}

// ---------------- routing: one wave per user; 16 lanes x 4 edges per iter ----------
// lane = 16*q + r: group q handles edge j0+q, lane holds dims [4r,4r+4).
// Pass 0 fused with LDS staging of the first RCAP rows; passes 1,2 and the final
// pass read those rows from LDS (deg>RCAP tail falls back to the gather path).
__global__ void __launch_bounds__(256) k_route(
        const float* __restrict__ Gum, const float* __restrict__ gim,
        const int* __restrict__ rptr, const int2* __restrict__ csr,
        float* __restrict__ gum_out, float* __restrict__ gu,
        float* __restrict__ expw_csc, int NU) {
    __shared__ float tile[4 * RCAP * 64];    // 16 KB: 4 waves x 16 rows x 64 f32
    int wid = (blockIdx.x * blockDim.x + threadIdx.x) >> 6;
    int lane = threadIdx.x & 63;
    if (wid >= NU) return;
    const int q = lane >> 4, r = lane & 15;
    float* my = tile + (threadIdx.x >> 6) * (RCAP * 64);
    const size_t ubase = (size_t)wid * 64 + 4 * r;

    float4 gl = *(const float4*)(Gum + ubase);
    float s2 = grp16_sum(gl.x * gl.x + gl.y * gl.y + gl.z * gl.z + gl.w * gl.w);
    float inv = 1.0f / fmaxf(sqrtf(s2), 1e-12f);
    gl.x *= inv; gl.y *= inv; gl.z *= inv; gl.w *= inv;

    const int st = rptr[wid], en = rptr[wid + 1];
    const int enc = min(en, st + RCAP);      // staged prefix

    // ---- pass 0 (fused with staging): gather gim rows, stash first RCAP in LDS ----
    {
        float s = 0.f;
        float4 acc = make_float4(0.f, 0.f, 0.f, 0.f);
        for (int j0 = st; j0 < en; j0 += 4) {
            int j = j0 + q;
            bool valid = j < en;
            int c = valid ? csr[j].x : 0;
            float4 gv = *(const float4*)(gim + (size_t)c * 64 + 4 * r);
            if (j < enc) *(float4*)(my + (j - st) * 64 + 4 * r) = gv;
            float d = grp16_sum(gl.x * gv.x + gl.y * gv.y + gl.z * gv.z + gl.w * gv.w);
            float w = d > 0.f ? d : 0.01f * d;
            float ew = valid ? __expf(w) : 0.f;
            s += ew;
            acc.x += ew * gv.x; acc.y += ew * gv.y;
            acc.z += ew * gv.z; acc.w += ew * gv.w;
        }
        s = xgrp_sum(s);
        acc = xgrp_sum4(acc);
        float invs = 1.0f / (s + 1e-16f);
        gl.x += acc.x * invs; gl.y += acc.y * invs;
        gl.z += acc.z * invs; gl.w += acc.w * invs;
        s2 = grp16_sum(gl.x * gl.x + gl.y * gl.y + gl.z * gl.z + gl.w * gl.w);
        inv = 1.0f / fmaxf(sqrtf(s2), 1e-12f);
        gl.x *= inv; gl.y *= inv; gl.z *= inv; gl.w *= inv;
    }

    // ---- passes 1,2: neighbor rows from LDS (fallback gather past RCAP) ----
    for (int it = 0; it < 2; ++it) {
        float s = 0.f;
        float4 acc = make_float4(0.f, 0.f, 0.f, 0.f);
        for (int j0 = st; j0 < en; j0 += 4) {
            int j = j0 + q;
            bool valid = j < en;
            float4 gv;
            if (j < enc) {
                gv = *(const float4*)(my + (j - st) * 64 + 4 * r);
            } else {
                int c = valid ? csr[j].x : 0;
                gv = *(const float4*)(gim + (size_t)c * 64 + 4 * r);
            }
            float d = grp16_sum(gl.x * gv.x + gl.y * gv.y + gl.z * gv.z + gl.w * gv.w);
            float w = d > 0.f ? d : 0.01f * d;
            float ew = valid ? __expf(w) : 0.f;
            s += ew;
            acc.x += ew * gv.x; acc.y += ew * gv.y;
            acc.z += ew * gv.z; acc.w += ew * gv.w;
        }
        s = xgrp_sum(s);
        acc = xgrp_sum4(acc);
        float invs = 1.0f / (s + 1e-16f);
        gl.x += acc.x * invs; gl.y += acc.y * invs;
        gl.z += acc.z * invs; gl.w += acc.w * invs;
        s2 = grp16_sum(gl.x * gl.x + gl.y * gl.y + gl.z * gl.z + gl.w * gl.w);
        inv = 1.0f / fmaxf(sqrtf(s2), 1e-12f);
        gl.x *= inv; gl.y *= inv; gl.z *= inv; gl.w *= inv;
    }
    if (q == 0) *(float4*)(gum_out + ubase) = gl;

    // ---- final layer, user side: exp(w) -> CSC slot, emit gu ----
    float s = 0.f;
    float4 acc = make_float4(0.f, 0.f, 0.f, 0.f);
    for (int j0 = st; j0 < en; j0 += 4) {
        int j = j0 + q;
        bool valid = j < en;
        float4 gv;
        if (j < enc) {
            gv = *(const float4*)(my + (j - st) * 64 + 4 * r);
        } else {
            int c = valid ? csr[j].x : 0;
            gv = *(const float4*)(gim + (size_t)c * 64 + 4 * r);
        }
        float d = grp16_sum(gl.x * gv.x + gl.y * gv.y + gl.z * gv.z + gl.w * gv.w);
        float w = d > 0.f ? d : 0.01f * d;
        float ew = valid ? __expf(w) : 0.f;
        if (valid && r == 0) expw_csc[csr[j].y] = ew;
        s += ew;
        acc.x += ew * gv.x; acc.y += ew * gv.y;
        acc.z += ew * gv.z; acc.w += ew * gv.w;
    }
    s = xgrp_sum(s);
    acc = xgrp_sum4(acc);
    float invs = 1.0f / (s + 1e-16f);
    if (q == 0) {
        float4 o = make_float4(gl.x + acc.x * invs, gl.y + acc.y * invs,
                               gl.z + acc.z * invs, gl.w + acc.w * invs);
        *(float4*)(gu + ubase) = o;
    }
}

// ---------------- final layer, item side: one wave per item; 4 edges/iter ---------
__global__ void k_item(const float* __restrict__ gum, const float* __restrict__ gim,
                       const int* __restrict__ cptr, const int* __restrict__ csc_r,
                       const float* __restrict__ expw_csc,
                       float* __restrict__ gi, int NI) {
    int wid = (blockIdx.x * blockDim.x + threadIdx.x) >> 6;
    int lane = threadIdx.x & 63;
    if (wid >= NI) return;
    const int q = lane >> 4, r = lane & 15;
    const int st = cptr[wid], en = cptr[wid + 1];
    float s = 0.f;
    float4 acc = make_float4(0.f, 0.f, 0.f, 0.f);
    for (int j0 = st; j0 < en; j0 += 4) {
        int j = j0 + q;
        bool valid = j < en;
        int rr = valid ? csc_r[j] : 0;
        float ew = valid ? expw_csc[j] : 0.f;
        float4 gv = *(const float4*)(gum + (size_t)rr * 64 + 4 * r);
        s += ew;
        acc.x += ew * gv.x; acc.y += ew * gv.y;
        acc.z += ew * gv.z; acc.w += ew * gv.w;
    }
    s = xgrp_sum(s);
    acc = xgrp_sum4(acc);
    float invs = 1.0f / (s + 1e-16f);
    if (q == 0) {
        const size_t ib = (size_t)wid * 64 + 4 * r;
        float4 gm = *(const float4*)(gim + ib);
        float4 o = make_float4(gm.x + acc.x * invs, gm.y + acc.y * invs,
                               gm.z + acc.z * invs, gm.w + acc.w * invs);
        *(float4*)(gi + ib) = o;
    }
}

// ---------------- output: xui[b] = dot(gu[user[b]], gi[pos[b]]) ----------------
__global__ void k_out(const float* __restrict__ gu, const float* __restrict__ gi,
                      const int* __restrict__ user, const int* __restrict__ pos,
                      float* __restrict__ out, int B) {
    int wid = (blockIdx.x * blockDim.x + threadIdx.x) >> 6;
    int lane = threadIdx.x & 63;
    if (wid >= B) return;
    float v = gu[(size_t)user[wid] * 64 + lane] * gi[(size_t)pos[wid] * 64 + lane];
#pragma unroll
    for (int o = 32; o > 0; o >>= 1) v += __shfl_xor(v, o, 64);
    if (lane == 0) out[wid] = v;
}

extern "C" void kernel_launch(void* const* d_in, const int* in_sizes, int n_in,
                              void* d_out, int out_size, void* d_ws, size_t ws_size,
                              hipStream_t stream) {
    const float* Gum  = (const float*)d_in[0];
    const float* feat = (const float*)d_in[1];
    const float* W    = (const float*)d_in[2];
    const float* bias = (const float*)d_in[3];
    const int* rows   = (const int*)d_in[4];
    const int* cols   = (const int*)d_in[5];
    const int* user   = (const int*)d_in[6];
    const int* pos    = (const int*)d_in[7];
    float* out = (float*)d_out;

    const int D  = in_sizes[3];          // 64
    const int NU = in_sizes[0] / D;      // 100000
    const int F  = in_sizes[2] / D;      // 2048
    const int NI = in_sizes[1] / F;      // 50000
    const int E  = in_sizes[4];          // 2000000
    const int B  = in_sizes[6];          // 4096

    char* p = (char*)d_ws;
    auto alloc = [&](size_t bytes) -> void* {
        void* r = (void*)p;
        p += (bytes + 255) / 256 * 256;
        return r;
    };
    float* gum     = (float*)alloc((size_t)NU * 64 * 4);
    float* gim     = (float*)alloc((size_t)NI * 64 * 4);
    float* gu      = (float*)alloc((size_t)NU * 64 * 4);
    float* gi      = (float*)alloc((size_t)NI * 64 * 4);
    float* expw    = (float*)alloc((size_t)E * 4);        // CSC-ordered
    int* rptr      = (int*)alloc((size_t)(NU + 1) * 4);
    int* cptr      = (int*)alloc((size_t)(NI + 1) * 4);
    int* cu        = (int*)alloc((size_t)NU * 4);
    int* ci        = (int*)alloc((size_t)NI * 4);
    int* ranku     = (int*)alloc((size_t)E * 4);
    int* ranki     = (int*)alloc((size_t)E * 4);
    int2* csr      = (int2*)alloc((size_t)E * 8);         // {col, csc_pos}
    int* csc_r     = (int*)alloc((size_t)E * 4);
    int* bsumU     = (int*)alloc(1024 * 4);
    int* bscanU    = (int*)alloc(1024 * 4);
    int* bsumI     = (int*)alloc(1024 * 4);
    int* bscanI    = (int*)alloc(1024 * 4);

    const int gU = (NU + 255) / 256;   // 391 (<=512 for k_bscan)
    const int gI = (NI + 255) / 256;   // 196

    hipMemsetAsync(cu, 0, (size_t)NU * 4, stream);
    hipMemsetAsync(ci, 0, (size_t)NI * 4, stream);
    k_hist<<<2048, 256, 0, stream>>>(rows, cols, E, cu, ci, ranku, ranki);

    k_bsum<<<gU, 256, 0, stream>>>(cu, NU, bsumU);
    k_bscan<<<1, 512, 0, stream>>>(bsumU, gU, bscanU);
    k_scan2<<<gU, 256, 0, stream>>>(cu, NU, bscanU, rptr);

    k_bsum<<<gI, 256, 0, stream>>>(ci, NI, bsumI);
    k_bscan<<<1, 512, 0, stream>>>(bsumI, gI, bscanI);
    k_scan2<<<gI, 256, 0, stream>>>(ci, NI, bscanI, cptr);

    k_scatter<<<2048, 256, 0, stream>>>(rows, cols, E, ranku, ranki, rptr, cptr, csr, csc_r);

    k_gim<<<(NI + 63) / 64, 256, 0, stream>>>(feat, W, bias, gim, NI, F);
    k_route<<<(NU + 3) / 4, 256, 0, stream>>>(Gum, gim, rptr, csr, gum, gu, expw, NU);
    k_item<<<(NI + 3) / 4, 256, 0, stream>>>(gum, gim, cptr, csc_r, expw, gi, NI);
    k_out<<<(B + 3) / 4, 256, 0, stream>>>(gu, gi, user, pos, out, B);
}

// Round 12
// 1284.269 us; speedup vs baseline: 1.0814x; 1.0006x over previous
//
#include <hip/hip_runtime.h>
#include <math.h>

#define RCAP 16   // LDS-staged rows/wave in k_route (16KB/block -> occupancy-neutral)

// ---------------- wave helpers (wave = 64 on gfx950) ----------------
__device__ __forceinline__ int wsumi(int v) {
#pragma unroll
    for (int o = 32; o > 0; o >>= 1) v += __shfl_xor(v, o, 64);
    return v;
}
__device__ __forceinline__ float grp16_sum(float v) {
    v += __shfl_xor(v, 1, 64);
    v += __shfl_xor(v, 2, 64);
    v += __shfl_xor(v, 4, 64);
    v += __shfl_xor(v, 8, 64);
    return v;
}
__device__ __forceinline__ float xgrp_sum(float v) {
    v += __shfl_xor(v, 16, 64);
    v += __shfl_xor(v, 32, 64);
    return v;
}
__device__ __forceinline__ float4 xgrp_sum4(float4 a) {
    a.x = xgrp_sum(a.x); a.y = xgrp_sum(a.y);
    a.z = xgrp_sum(a.z); a.w = xgrp_sum(a.w);
    return a;
}

// ---------------- gim = l2norm(leaky(l2norm(feat) @ W + b)) ----------------
// BM=32 rows/block -> 1563 blocks (~6/CU, was 782 at BM=64: grid-limited 26% occ).
// As stored transposed [kk][row] (+2 pad: 8B-aligned float2 reads, 2-way-free writes).
__global__ void __launch_bounds__(256) k_gim(
        const float* __restrict__ feat, const float* __restrict__ W,
        const float* __restrict__ bias, float* __restrict__ gim,
        int NI, int F) {
    __shared__ float As[32][34];   // [kk][row], +2 pad (alignment + bank spread)
    __shared__ float Bs[32][64];   // [kk][col]
    __shared__ float rn[32];
    const int tid = threadIdx.x;
    const int r0 = blockIdx.x * 32;
    const int lrow = tid >> 3, lk4 = (tid & 7) * 4;   // feat load: row 0..31, k 0..28
    const int tr = tid >> 4, tc = tid & 15;           // compute: rows {2tr,2tr+1}, cols tc*4..+3
    float acc[2][4] = {{0.f,0.f,0.f,0.f},{0.f,0.f,0.f,0.f}};
    float ssq = 0.f;
    const bool rowok = (r0 + lrow) < NI;
    const float* featp = feat + (size_t)(r0 + lrow) * F + lk4;

    for (int kb = 0; kb < F; kb += 32) {
        float4 av = make_float4(0.f, 0.f, 0.f, 0.f);
        if (rowok) av = *(const float4*)(featp + kb);
        float4 bv0 = *(const float4*)(W + (size_t)(kb + tr) * 64 + tc * 4);
        float4 bv1 = *(const float4*)(W + (size_t)(kb + 16 + tr) * 64 + tc * 4);
        __syncthreads();   // previous tile's reads done
        As[lk4 + 0][lrow] = av.x; As[lk4 + 1][lrow] = av.y;
        As[lk4 + 2][lrow] = av.z; As[lk4 + 3][lrow] = av.w;
        ssq += av.x * av.x + av.y * av.y + av.z * av.z + av.w * av.w;
        *(float4*)&Bs[tr][tc * 4] = bv0;
        *(float4*)&Bs[16 + tr][tc * 4] = bv1;
        __syncthreads();   // tile visible
#pragma unroll
        for (int kk = 0; kk < 32; ++kk) {
            float2 a = *(const float2*)&As[kk][tr * 2];
            float4 b = *(const float4*)&Bs[kk][tc * 4];
            acc[0][0] += a.x * b.x; acc[0][1] += a.x * b.y;
            acc[0][2] += a.x * b.z; acc[0][3] += a.x * b.w;
            acc[1][0] += a.y * b.x; acc[1][1] += a.y * b.y;
            acc[1][2] += a.y * b.z; acc[1][3] += a.y * b.w;
        }
    }
    // feat-row sumsq: 8 lanes per row (consecutive), reduce over tid&7
    ssq += __shfl_xor(ssq, 1, 64);
    ssq += __shfl_xor(ssq, 2, 64);
    ssq += __shfl_xor(ssq, 4, 64);
    if ((tid & 7) == 0) rn[lrow] = ssq;
    __syncthreads();

    float bc[4];
#pragma unroll
    for (int j = 0; j < 4; ++j) bc[j] = bias[tc * 4 + j];
#pragma unroll
    for (int i = 0; i < 2; ++i) {
        int r = tr * 2 + i;
        float inv = 1.0f / fmaxf(sqrtf(rn[r]), 1e-12f);
        float v[4], rs = 0.f;
#pragma unroll
        for (int j = 0; j < 4; ++j) {
            float x = acc[i][j] * inv + bc[j];
            x = x > 0.f ? x : 0.01f * x;   // leaky_relu
            v[j] = x; rs += x * x;
        }
        // output-row l2norm: 16 lanes share row r (same tr)
        rs += __shfl_xor(rs, 1, 64); rs += __shfl_xor(rs, 2, 64);
        rs += __shfl_xor(rs, 4, 64); rs += __shfl_xor(rs, 8, 64);
        float sc = 1.0f / fmaxf(sqrtf(rs), 1e-12f);
        int gr = r0 + r;
        if (gr < NI) {
            float4 o = make_float4(v[0] * sc, v[1] * sc, v[2] * sc, v[3] * sc);
            *(float4*)(gim + (size_t)gr * 64 + tc * 4) = o;
        }
    }
}

// ---------------- CSR/CSC build ----------------
__global__ void k_hist(const int* __restrict__ rows, const int* __restrict__ cols, int E,
                       int* __restrict__ cu, int* __restrict__ ci,
                       int* __restrict__ ranku, int* __restrict__ ranki) {
    for (int e = blockIdx.x * blockDim.x + threadIdx.x; e < E; e += gridDim.x * blockDim.x) {
        ranku[e] = atomicAdd(&cu[rows[e]], 1);
        ranki[e] = atomicAdd(&ci[cols[e]], 1);
    }
}

__global__ void k_bsum(const int* __restrict__ cnt, int n, int* __restrict__ bsum) {
    int i = blockIdx.x * 256 + threadIdx.x;
    int v = (i < n) ? cnt[i] : 0;
    v = wsumi(v);
    __shared__ int sm[4];
    if ((threadIdx.x & 63) == 0) sm[threadIdx.x >> 6] = v;
    __syncthreads();
    if (threadIdx.x == 0) bsum[blockIdx.x] = sm[0] + sm[1] + sm[2] + sm[3];
}

// single block, nb <= 512
__global__ void k_bscan(const int* __restrict__ bsum, int nb, int* __restrict__ bscan) {
    __shared__ int sd[512];
    int tid = threadIdx.x;
    int v = (tid < nb) ? bsum[tid] : 0;
    sd[tid] = v;
    __syncthreads();
    for (int off = 1; off < 512; off <<= 1) {
        int t = (tid >= off) ? sd[tid - off] : 0;
        __syncthreads();
        sd[tid] += t;
        __syncthreads();
    }
    if (tid < nb) bscan[tid] = sd[tid] - v;   // exclusive
}

__global__ void k_scan2(const int* __restrict__ cnt, int n, const int* __restrict__ bscan,
                        int* __restrict__ ptr) {
    __shared__ int sd[256];
    int tid = threadIdx.x;
    int i = blockIdx.x * 256 + tid;
    int v = (i < n) ? cnt[i] : 0;
    sd[tid] = v;
    __syncthreads();
    for (int off = 1; off < 256; off <<= 1) {
        int t = (tid >= off) ? sd[tid - off] : 0;
        __syncthreads();
        sd[tid] += t;
        __syncthreads();
    }
    if (i < n) ptr[i + 1] = sd[tid] + bscan[blockIdx.x];
    if (blockIdx.x == 0 && tid == 0) ptr[0] = 0;
}

// atomic-free scatter: csr[pu] = {col, csc_pos}; csc_r[pi] = row.
__global__ void k_scatter(const int* __restrict__ rows, const int* __restrict__ cols, int E,
                          const int* __restrict__ ranku, const int* __restrict__ ranki,
                          const int* __restrict__ rptr, const int* __restrict__ cptr,
                          int2* __restrict__ csr, int* __restrict__ csc_r) {
    for (int e = blockIdx.x * blockDim.x + threadIdx.x; e < E; e += gridDim.x * blockDim.x) {
        int r = rows[e], c = cols[e];
        int pu = rptr[r] + ranku[e];
        int pi = cptr[c] + ranki[e];
        csr[pu] = make_int2(c, pi);
        csc_r[pi] = r;
    }
}

// ---------------- routing: one wave per user; 16 lanes x 4 edges per iter ----------
// Pass 0 fused with LDS staging of the first RCAP rows; passes 1,2 and the final
// pass read those rows from LDS (deg>RCAP tail falls back to the gather path).
__global__ void __launch_bounds__(256) k_route(
        const float* __restrict__ Gum, const float* __restrict__ gim,
        const int* __restrict__ rptr, const int2* __restrict__ csr,
        float* __restrict__ gum_out, float* __restrict__ gu,
        float* __restrict__ expw_csc, int NU) {
    __shared__ float tile[4 * RCAP * 64];    // 16 KB: 4 waves x 16 rows x 64 f32
    int wid = (blockIdx.x * blockDim.x + threadIdx.x) >> 6;
    int lane = threadIdx.x & 63;
    if (wid >= NU) return;
    const int q = lane >> 4, r = lane & 15;
    float* my = tile + (threadIdx.x >> 6) * (RCAP * 64);
    const size_t ubase = (size_t)wid * 64 + 4 * r;

    float4 gl = *(const float4*)(Gum + ubase);
    float s2 = grp16_sum(gl.x * gl.x + gl.y * gl.y + gl.z * gl.z + gl.w * gl.w);
    float inv = 1.0f / fmaxf(sqrtf(s2), 1e-12f);
    gl.x *= inv; gl.y *= inv; gl.z *= inv; gl.w *= inv;

    const int st = rptr[wid], en = rptr[wid + 1];
    const int enc = min(en, st + RCAP);      // staged prefix

    // ---- pass 0 (fused with staging): gather gim rows, stash first RCAP in LDS ----
    {
        float s = 0.f;
        float4 acc = make_float4(0.f, 0.f, 0.f, 0.f);
        for (int j0 = st; j0 < en; j0 += 4) {
            int j = j0 + q;
            bool valid = j < en;
            int c = valid ? csr[j].x : 0;
            float4 gv = *(const float4*)(gim + (size_t)c * 64 + 4 * r);
            if (j < enc) *(float4*)(my + (j - st) * 64 + 4 * r) = gv;
            float d = grp16_sum(gl.x * gv.x + gl.y * gv.y + gl.z * gv.z + gl.w * gv.w);
            float w = d > 0.f ? d : 0.01f * d;
            float ew = valid ? __expf(w) : 0.f;
            s += ew;
            acc.x += ew * gv.x; acc.y += ew * gv.y;
            acc.z += ew * gv.z; acc.w += ew * gv.w;
        }
        s = xgrp_sum(s);
        acc = xgrp_sum4(acc);
        float invs = 1.0f / (s + 1e-16f);
        gl.x += acc.x * invs; gl.y += acc.y * invs;
        gl.z += acc.z * invs; gl.w += acc.w * invs;
        s2 = grp16_sum(gl.x * gl.x + gl.y * gl.y + gl.z * gl.z + gl.w * gl.w);
        inv = 1.0f / fmaxf(sqrtf(s2), 1e-12f);
        gl.x *= inv; gl.y *= inv; gl.z *= inv; gl.w *= inv;
    }

    // ---- passes 1,2: neighbor rows from LDS (fallback gather past RCAP) ----
    for (int it = 0; it < 2; ++it) {
        float s = 0.f;
        float4 acc = make_float4(0.f, 0.f, 0.f, 0.f);
        for (int j0 = st; j0 < en; j0 += 4) {
            int j = j0 + q;
            bool valid = j < en;
            float4 gv;
            if (j < enc) {
                gv = *(const float4*)(my + (j - st) * 64 + 4 * r);
            } else {
                int c = valid ? csr[j].x : 0;
                gv = *(const float4*)(gim + (size_t)c * 64 + 4 * r);
            }
            float d = grp16_sum(gl.x * gv.x + gl.y * gv.y + gl.z * gv.z + gl.w * gv.w);
            float w = d > 0.f ? d : 0.01f * d;
            float ew = valid ? __expf(w) : 0.f;
            s += ew;
            acc.x += ew * gv.x; acc.y += ew * gv.y;
            acc.z += ew * gv.z; acc.w += ew * gv.w;
        }
        s = xgrp_sum(s);
        acc = xgrp_sum4(acc);
        float invs = 1.0f / (s + 1e-16f);
        gl.x += acc.x * invs; gl.y += acc.y * invs;
        gl.z += acc.z * invs; gl.w += acc.w * invs;
        s2 = grp16_sum(gl.x * gl.x + gl.y * gl.y + gl.z * gl.z + gl.w * gl.w);
        inv = 1.0f / fmaxf(sqrtf(s2), 1e-12f);
        gl.x *= inv; gl.y *= inv; gl.z *= inv; gl.w *= inv;
    }
    if (q == 0) *(float4*)(gum_out + ubase) = gl;

    // ---- final layer, user side: exp(w) -> CSC slot, emit gu ----
    float s = 0.f;
    float4 acc = make_float4(0.f, 0.f, 0.f, 0.f);
    for (int j0 = st; j0 < en; j0 += 4) {
        int j = j0 + q;
        bool valid = j < en;
        float4 gv;
        if (j < enc) {
            gv = *(const float4*)(my + (j - st) * 64 + 4 * r);
        } else {
            int c = valid ? csr[j].x : 0;
            gv = *(const float4*)(gim + (size_t)c * 64 + 4 * r);
        }
        float d = grp16_sum(gl.x * gv.x + gl.y * gv.y + gl.z * gv.z + gl.w * gv.w);
        float w = d > 0.f ? d : 0.01f * d;
        float ew = valid ? __expf(w) : 0.f;
        if (valid && r == 0) expw_csc[csr[j].y] = ew;
        s += ew;
        acc.x += ew * gv.x; acc.y += ew * gv.y;
        acc.z += ew * gv.z; acc.w += ew * gv.w;
    }
    s = xgrp_sum(s);
    acc = xgrp_sum4(acc);
    float invs = 1.0f / (s + 1e-16f);
    if (q == 0) {
        float4 o = make_float4(gl.x + acc.x * invs, gl.y + acc.y * invs,
                               gl.z + acc.z * invs, gl.w + acc.w * invs);
        *(float4*)(gu + ubase) = o;
    }
}

// ---------------- final layer, item side: one wave per item; 4 edges/iter ---------
__global__ void k_item(const float* __restrict__ gum, const float* __restrict__ gim,
                       const int* __restrict__ cptr, const int* __restrict__ csc_r,
                       const float* __restrict__ expw_csc,
                       float* __restrict__ gi, int NI) {
    int wid = (blockIdx.x * blockDim.x + threadIdx.x) >> 6;
    int lane = threadIdx.x & 63;
    if (wid >= NI) return;
    const int q = lane >> 4, r = lane & 15;
    const int st = cptr[wid], en = cptr[wid + 1];
    float s = 0.f;
    float4 acc = make_float4(0.f, 0.f, 0.f, 0.f);
    for (int j0 = st; j0 < en; j0 += 4) {
        int j = j0 + q;
        bool valid = j < en;
        int rr = valid ? csc_r[j] : 0;
        float ew = valid ? expw_csc[j] : 0.f;
        float4 gv = *(const float4*)(gum + (size_t)rr * 64 + 4 * r);
        s += ew;
        acc.x += ew * gv.x; acc.y += ew * gv.y;
        acc.z += ew * gv.z; acc.w += ew * gv.w;
    }
    s = xgrp_sum(s);
    acc = xgrp_sum4(acc);
    float invs = 1.0f / (s + 1e-16f);
    if (q == 0) {
        const size_t ib = (size_t)wid * 64 + 4 * r;
        float4 gm = *(const float4*)(gim + ib);
        float4 o = make_float4(gm.x + acc.x * invs, gm.y + acc.y * invs,
                               gm.z + acc.z * invs, gm.w + acc.w * invs);
        *(float4*)(gi + ib) = o;
    }
}

// ---------------- output: xui[b] = dot(gu[user[b]], gi[pos[b]]) ----------------
__global__ void k_out(const float* __restrict__ gu, const float* __restrict__ gi,
                      const int* __restrict__ user, const int* __restrict__ pos,
                      float* __restrict__ out, int B) {
    int wid = (blockIdx.x * blockDim.x + threadIdx.x) >> 6;
    int lane = threadIdx.x & 63;
    if (wid >= B) return;
    float v = gu[(size_t)user[wid] * 64 + lane] * gi[(size_t)pos[wid] * 64 + lane];
#pragma unroll
    for (int o = 32; o > 0; o >>= 1) v += __shfl_xor(v, o, 64);
    if (lane == 0) out[wid] = v;
}

extern "C" void kernel_launch(void* const* d_in, const int* in_sizes, int n_in,
                              void* d_out, int out_size, void* d_ws, size_t ws_size,
                              hipStream_t stream) {
    const float* Gum  = (const float*)d_in[0];
    const float* feat = (const float*)d_in[1];
    const float* W    = (const float*)d_in[2];
    const float* bias = (const float*)d_in[3];
    const int* rows   = (const int*)d_in[4];
    const int* cols   = (const int*)d_in[5];
    const int* user   = (const int*)d_in[6];
    const int* pos    = (const int*)d_in[7];
    float* out = (float*)d_out;

    const int D  = in_sizes[3];          // 64
    const int NU = in_sizes[0] / D;      // 100000
    const int F  = in_sizes[2] / D;      // 2048
    const int NI = in_sizes[1] / F;      // 50000
    const int E  = in_sizes[4];          // 2000000
    const int B  = in_sizes[6];          // 4096

    char* p = (char*)d_ws;
    auto alloc = [&](size_t bytes) -> void* {
        void* r = (void*)p;
        p += (bytes + 255) / 256 * 256;
        return r;
    };
    float* gum     = (float*)alloc((size_t)NU * 64 * 4);
    float* gim     = (float*)alloc((size_t)NI * 64 * 4);
    float* gu      = (float*)alloc((size_t)NU * 64 * 4);
    float* gi      = (float*)alloc((size_t)NI * 64 * 4);
    float* expw    = (float*)alloc((size_t)E * 4);        // CSC-ordered
    int* rptr      = (int*)alloc((size_t)(NU + 1) * 4);
    int* cptr      = (int*)alloc((size_t)(NI + 1) * 4);
    int* cu        = (int*)alloc((size_t)NU * 4);
    int* ci        = (int*)alloc((size_t)NI * 4);
    int* ranku     = (int*)alloc((size_t)E * 4);
    int* ranki     = (int*)alloc((size_t)E * 4);
    int2* csr      = (int2*)alloc((size_t)E * 8);         // {col, csc_pos}
    int* csc_r     = (int*)alloc((size_t)E * 4);
    int* bsumU     = (int*)alloc(1024 * 4);
    int* bscanU    = (int*)alloc(1024 * 4);
    int* bsumI     = (int*)alloc(1024 * 4);
    int* bscanI    = (int*)alloc(1024 * 4);

    const int gU = (NU + 255) / 256;   // 391 (<=512 for k_bscan)
    const int gI = (NI + 255) / 256;   // 196

    hipMemsetAsync(cu, 0, (size_t)NU * 4, stream);
    hipMemsetAsync(ci, 0, (size_t)NI * 4, stream);
    k_hist<<<2048, 256, 0, stream>>>(rows, cols, E, cu, ci, ranku, ranki);

    k_bsum<<<gU, 256, 0, stream>>>(cu, NU, bsumU);
    k_bscan<<<1, 512, 0, stream>>>(bsumU, gU, bscanU);
    k_scan2<<<gU, 256, 0, stream>>>(cu, NU, bscanU, rptr);

    k_bsum<<<gI, 256, 0, stream>>>(ci, NI, bsumI);
    k_bscan<<<1, 512, 0, stream>>>(bsumI, gI, bscanI);
    k_scan2<<<gI, 256, 0, stream>>>(ci, NI, bscanI, cptr);

    k_scatter<<<2048, 256, 0, stream>>>(rows, cols, E, ranku, ranki, rptr, cptr, csr, csc_r);

    k_gim<<<(NI + 31) / 32, 256, 0, stream>>>(feat, W, bias, gim, NI, F);
    k_route<<<(NU + 3) / 4, 256, 0, stream>>>(Gum, gim, rptr, csr, gum, gu, expw, NU);
    k_item<<<(NI + 3) / 4, 256, 0, stream>>>(gum, gim, cptr, csc_r, expw, gi, NI);
    k_out<<<(B + 3) / 4, 256, 0, stream>>>(gu, gi, user, pos, out, B);
}